// Round 13
// baseline (154.610 us; speedup 1.0000x reference)
//
#include <hip/hip_runtime.h>

#define DD 256
#define BB 8
#define SS 1024
#define XSTRIDE 264   // f16 elems per LDS row (528 B, 16B-aligned)
#define RSTRIDE 260   // f32 elems per residual LDS row (1040 B, 16B-aligned)

// ws layout per layer (bytes): Mtab 128K | Ptab 128K | Itab 256K = 512K
#define LAYER_BYTES 524288
#define PTAB_OFF    131072
#define ITAB_OFF    262144
#define WS_NEEDED   (2 * LAYER_BYTES)

typedef _Float16 half8  __attribute__((ext_vector_type(8)));
typedef _Float16 half2t __attribute__((ext_vector_type(2)));
typedef __fp16   fp16x2 __attribute__((ext_vector_type(2)));
typedef __attribute__((ext_vector_type(4))) float float4v;

union h8u { half8 h; half2t h2[4]; };

__device__ __forceinline__ half2t pkrtz(float a, float b) {
    union { fp16x2 f; half2t h; } cv;
    cv.f = __builtin_amdgcn_cvt_pkrtz(a, b);
    return cv.h;
}

__device__ __forceinline__ float cosrev(float x) {   // cos(2*pi*x), any x
    return __builtin_amdgcn_cosf(__builtin_amdgcn_fractf(x));
}
__device__ __forceinline__ float cosq(float x) {     // cos(2*pi*x), x in [0,1)
    return __builtin_amdgcn_cosf(x);
}

// Fragment-ordered tables: for gi = (kt*16 + wt)*64 + lane,
// lane = quad*16 + l15, n = 16*wt+l15, j0 = kt*32+quad*8:
//   Mtab[gi] = M[n][j0..j0+7] (f16), Ptab[gi] = P[n][j0..j0+7] (f16),
//   Itab[2*gi..2*gi+1] = 1/(n*256 + j0 + e + 2), e=0..7 (f32)
__global__ void build_tabs(const float* __restrict__ M1, const float* __restrict__ P1,
                           const float* __restrict__ M2, const float* __restrict__ P2,
                           char* __restrict__ ws)
{
    int gid   = blockIdx.x * 256 + threadIdx.x;   // 0..16383
    int layer = gid >> 13;
    int gi    = gid & 8191;
    int idx   = gi >> 6;                           // kt*16 + wt
    int lane  = gi & 63;
    int wt    = idx & 15;
    int l15   = lane & 15, quad = lane >> 4;
    int kt    = idx >> 4;
    int n     = 16 * wt + l15;
    int j0    = kt * 32 + quad * 8;

    const float* Msrc = layer ? M2 : M1;
    const float* Psrc = layer ? P2 : P1;

    h8u mh, ph;
    float iv[8];
    #pragma unroll
    for (int e = 0; e < 4; ++e) {
        float ma = Msrc[(size_t)n * DD + j0 + 2 * e];
        float mb = Msrc[(size_t)n * DD + j0 + 2 * e + 1];
        float pa = Psrc[(size_t)n * DD + j0 + 2 * e];
        float pb = Psrc[(size_t)n * DD + j0 + 2 * e + 1];
        mh.h2[e] = pkrtz(ma, mb);
        ph.h2[e] = pkrtz(pa, pb);
        iv[2 * e]     = 1.0f / (float)(n * DD + j0 + 2 * e + 2);
        iv[2 * e + 1] = 1.0f / (float)(n * DD + j0 + 2 * e + 3);
    }
    char* base = ws + (size_t)layer * LAYER_BYTES;
    ((half8*)base)[gi]              = mh.h;
    ((half8*)(base + PTAB_OFF))[gi] = ph.h;
    float4* it = (float4*)(base + ITAB_OFF);
    it[2 * gi]     = make_float4(iv[0], iv[1], iv[2], iv[3]);
    it[2 * gi + 1] = make_float4(iv[4], iv[5], iv[6], iv[7]);
}

// Block = ONE s (grid 1024, 512 thr, 8 waves), bound (512,6) [budget 85 VGPR].
// r12 was WRITE-clean (8.2MB) but duty 41.5%: Itab/Ptab L2 loads were consumed
// immediately (no prefetch) -> ~200cy exposed per tile. This round adds ONLY the
// distance-1 pipeline: phase A prefetches Mtab/LDS-a; phase B's kt=0 loads are
// hoisted above LN (LN covers them) and each kt prefetches kt+1's Ptab/Itab/a.
// All prefetch state in NAMED scalars (no arrays -- r10's scratch trigger).
// VGPR est 68 <= 85; falsifier: WRITE > 15MB = spill -> revert to r12.
template<bool TABS>
__global__ __launch_bounds__(512, 6)
void fused_hierddpm(const float* __restrict__ seq,
                    const float* __restrict__ M1, const float* __restrict__ P1,
                    const float* __restrict__ g1, const float* __restrict__ be1,
                    const float* __restrict__ M2, const float* __restrict__ P2,
                    const float* __restrict__ g2, const float* __restrict__ be2,
                    const char* __restrict__ ws,
                    float* __restrict__ out)
{
    __shared__ __align__(16) _Float16 xsb[8][XSTRIDE];   // input / layer-out, f16
    __shared__ __align__(16) _Float16 xtb[8][XSTRIDE];   // LN'd xt, f16
    __shared__ __align__(16) float2 stats[8][8];         // [row][wave] (sum, sumsq)
    __shared__ __align__(16) float res_lds[8][RSTRIDE];  // f32 residual

    const int tid  = threadIdx.x;
    const int w    = tid >> 6;
    const int lane = tid & 63;
    const int l15  = lane & 15;
    const int l7   = l15 & 7;
    const int quad = lane >> 4;
    const int s    = blockIdx.x;
    const float k0 = (float)s;

    // ---- stage 8 rows (b = 0..7) at this s: one float4 per thread
    {
        const float4* seq4 = (const float4*)seq;
        int row = tid >> 6, j4 = tid & 63;
        float4 x = seq4[((size_t)row * SS + s) * 64 + j4];
        half2t* dst = (half2t*)&xsb[row][4 * j4];
        dst[0] = pkrtz(x.x, x.y);
        dst[1] = pkrtz(x.z, x.w);
        *(float4*)&res_lds[row][4 * j4] = x;
    }
    __syncthreads();

    #pragma unroll 1
    for (int layer = 0; layer < 2; ++layer) {
        const float* M  = layer ? M2  : M1;
        const float* P  = layer ? P2  : P1;
        const float* g  = layer ? g2  : g1;
        const float* be = layer ? be2 : be1;
        const char*  lbase = ws + (size_t)layer * LAYER_BYTES;
        const half8*  Mtab = (const half8*)lbase;
        const half8*  Ptab = (const half8*)(lbase + PTAB_OFF);
        const float4* Itab = (const float4*)(lbase + ITAB_OFF);

        // ======== phase A: xt = x @ M^T; wave owns n-tiles 2w, 2w+1 (d1-pipelined)
        float4v acc1[2];
        acc1[0] = (float4v){0.f, 0.f, 0.f, 0.f};
        acc1[1] = (float4v){0.f, 0.f, 0.f, 0.f};

        if (TABS) {
            half8 aN  = *(const half8*)&xsb[l7][quad * 8];
            half8 b0N = Mtab[(2 * w) * 64 + lane];
            half8 b1N = Mtab[(2 * w + 1) * 64 + lane];
            #pragma unroll 1
            for (int kt = 0; kt < 8; ++kt) {
                half8 aC = aN, b0C = b0N, b1C = b1N;
                if (kt < 7) {
                    aN  = *(const half8*)&xsb[l7][(kt + 1) * 32 + quad * 8];
                    b0N = Mtab[((kt + 1) * 16 + 2 * w) * 64 + lane];
                    b1N = Mtab[((kt + 1) * 16 + 2 * w + 1) * 64 + lane];
                }
                acc1[0] = __builtin_amdgcn_mfma_f32_16x16x32_f16(aC, b0C, acc1[0], 0, 0, 0);
                acc1[1] = __builtin_amdgcn_mfma_f32_16x16x32_f16(aC, b1C, acc1[1], 0, 0, 0);
            }
        } else {
            #pragma unroll 1
            for (int kt = 0; kt < 8; ++kt) {
                half8 a = *(const half8*)&xsb[l7][kt * 32 + quad * 8];
                #pragma unroll
                for (int t = 0; t < 2; ++t) {
                    int n = 16 * (2 * w + t) + l15;
                    const float4* Mr = (const float4*)M + ((size_t)n * 64 + kt * 8 + quad * 2);
                    float4 m0 = Mr[0], m1 = Mr[1];
                    h8u bb2;
                    bb2.h2[0] = pkrtz(m0.x, m0.y);
                    bb2.h2[1] = pkrtz(m0.z, m0.w);
                    bb2.h2[2] = pkrtz(m1.x, m1.y);
                    bb2.h2[3] = pkrtz(m1.z, m1.w);
                    acc1[t] = __builtin_amdgcn_mfma_f32_16x16x32_f16(a, bb2.h, acc1[t], 0, 0, 0);
                }
            }
        }

        // hoist phase-B kt=0 loads NOW: LayerNorm below covers their L2 latency
        half8 p0N, p1N;
        float4 i0aN, i0bN, i1aN, i1bN;
        if (TABS) {
            int g0 = (2 * w) * 64 + lane;
            int g1i = (2 * w + 1) * 64 + lane;
            p0N  = Ptab[g0];           p1N  = Ptab[g1i];
            i0aN = Itab[2 * g0];       i0bN = Itab[2 * g0 + 1];
            i1aN = Itab[2 * g1i];      i1bN = Itab[2 * g1i + 1];
        }

        // ======== LayerNorm (C rows m = quad*4+reg; rows 0-7 valid, on quads 0-1)
        #pragma unroll
        for (int reg = 0; reg < 4; ++reg) {
            float v0 = acc1[0][reg], v1 = acc1[1][reg];
            float sm = v0 + v1;
            float sq = fmaf(v0, v0, v1 * v1);
            #pragma unroll
            for (int off = 1; off < 16; off <<= 1) {
                sm += __shfl_xor(sm, off, 64);
                sq += __shfl_xor(sq, off, 64);
            }
            if (l15 == 0 && quad < 2) stats[quad * 4 + reg][w] = make_float2(sm, sq);
        }
        __syncthreads();
        if (quad < 2) {
            int c0i = 16 * (2 * w) + l15, c1i = c0i + 16;
            float gv0 = g[c0i], bv0 = be[c0i];
            float gv1 = g[c1i], bv1 = be[c1i];
            #pragma unroll
            for (int reg = 0; reg < 4; ++reg) {
                int m = quad * 4 + reg;
                const float4* s4 = (const float4*)&stats[m][0];
                float4 q0 = s4[0], q1 = s4[1], q2 = s4[2], q3 = s4[3];
                float sm = (q0.x + q0.z) + (q1.x + q1.z) + (q2.x + q2.z) + (q3.x + q3.z);
                float sq = (q0.y + q0.w) + (q1.y + q1.w) + (q2.y + q2.w) + (q3.y + q3.w);
                float mm = sm * (1.f / DD);
                float rs = rsqrtf(sq * (1.f / DD) - mm * mm + 1e-5f);
                xtb[m][c0i] = (_Float16)fmaf((acc1[0][reg] - mm) * rs, gv0, bv0);
                xtb[m][c1i] = (_Float16)fmaf((acc1[1][reg] - mm) * rs, gv1, bv1);
            }
        }
        __syncthreads();   // xtb ready for phase B

        // ======== phase B: Nk = xt @ W_s^T; W = P * cos(2*pi*s/p), 1/p from Itab
        float4v accS[2];
        accS[0] = (float4v){0.f, 0.f, 0.f, 0.f};
        accS[1] = (float4v){0.f, 0.f, 0.f, 0.f};

        if (TABS) {
            half8 aN = *(const half8*)&xtb[l7][quad * 8];
            #pragma unroll 1
            for (int kt = 0; kt < 8; ++kt) {
                half8 aC = aN;
                h8u p0C, p1C;
                p0C.h = p0N;  p1C.h = p1N;
                float4 i0a = i0aN, i0b = i0bN, i1a = i1aN, i1b = i1bN;
                if (kt < 7) {   // prefetch kt+1 (L2) before this kt's trans/VALU block
                    int g0 = ((kt + 1) * 16 + 2 * w) * 64 + lane;
                    int g1i = ((kt + 1) * 16 + 2 * w + 1) * 64 + lane;
                    aN   = *(const half8*)&xtb[l7][(kt + 1) * 32 + quad * 8];
                    p0N  = Ptab[g0];           p1N  = Ptab[g1i];
                    i0aN = Itab[2 * g0];       i0bN = Itab[2 * g0 + 1];
                    i1aN = Itab[2 * g1i];      i1bN = Itab[2 * g1i + 1];
                }
                // ---- t = 0 (w==0: p down to 2 -> exact range-reduce; else fract-free)
                {
                    h8u bA;
                    if (w == 0) {
                        bA.h2[0] = p0C.h2[0] * pkrtz(cosrev(k0 * i0a.x), cosrev(k0 * i0a.y));
                        bA.h2[1] = p0C.h2[1] * pkrtz(cosrev(k0 * i0a.z), cosrev(k0 * i0a.w));
                        bA.h2[2] = p0C.h2[2] * pkrtz(cosrev(k0 * i0b.x), cosrev(k0 * i0b.y));
                        bA.h2[3] = p0C.h2[3] * pkrtz(cosrev(k0 * i0b.z), cosrev(k0 * i0b.w));
                    } else {   // n >= 32 -> p >= 8194 > k: fract is identity
                        bA.h2[0] = p0C.h2[0] * pkrtz(cosq(k0 * i0a.x), cosq(k0 * i0a.y));
                        bA.h2[1] = p0C.h2[1] * pkrtz(cosq(k0 * i0a.z), cosq(k0 * i0a.w));
                        bA.h2[2] = p0C.h2[2] * pkrtz(cosq(k0 * i0b.x), cosq(k0 * i0b.y));
                        bA.h2[3] = p0C.h2[3] * pkrtz(cosq(k0 * i0b.z), cosq(k0 * i0b.w));
                    }
                    accS[0] = __builtin_amdgcn_mfma_f32_16x16x32_f16(aC, bA.h, accS[0], 0, 0, 0);
                }
                // ---- t = 1: n >= 16 -> p >= 4098 > k: fract-free
                {
                    h8u bB;
                    bB.h2[0] = p1C.h2[0] * pkrtz(cosq(k0 * i1a.x), cosq(k0 * i1a.y));
                    bB.h2[1] = p1C.h2[1] * pkrtz(cosq(k0 * i1a.z), cosq(k0 * i1a.w));
                    bB.h2[2] = p1C.h2[2] * pkrtz(cosq(k0 * i1b.x), cosq(k0 * i1b.y));
                    bB.h2[3] = p1C.h2[3] * pkrtz(cosq(k0 * i1b.z), cosq(k0 * i1b.w));
                    accS[1] = __builtin_amdgcn_mfma_f32_16x16x32_f16(aC, bB.h, accS[1], 0, 0, 0);
                }
            }
        } else {
            float fb0 = (float)((16 * (2 * w) + l15) * DD + quad * 8 + 2);
            float fb1 = fb0 + 16.0f * DD;
            #pragma unroll 1
            for (int kt = 0; kt < 8; ++kt) {
                half8 a = *(const half8*)&xtb[l7][kt * 32 + quad * 8];
                #pragma unroll
                for (int t = 0; t < 2; ++t) {
                    int n = 16 * (2 * w + t) + l15;
                    const float4* Pr = (const float4*)P + ((size_t)n * 64 + kt * 8 + quad * 2);
                    float4 p0 = Pr[0], p1 = Pr[1];
                    h8u pC;
                    pC.h2[0] = pkrtz(p0.x, p0.y);
                    pC.h2[1] = pkrtz(p0.z, p0.w);
                    pC.h2[2] = pkrtz(p1.x, p1.y);
                    pC.h2[3] = pkrtz(p1.z, p1.w);
                    float fb = (t == 0) ? fb0 : fb1;
                    h8u bA;
                    #pragma unroll
                    for (int e = 0; e < 4; ++e) {
                        float ra = __builtin_amdgcn_rcpf(fb + (float)(2 * e));
                        float rb = __builtin_amdgcn_rcpf(fb + (float)(2 * e + 1));
                        bA.h2[e] = pC.h2[e] * pkrtz(cosrev(k0 * ra), cosrev(k0 * rb));
                    }
                    accS[t] = __builtin_amdgcn_mfma_f32_16x16x32_f16(a, bA.h, accS[t], 0, 0, 0);
                }
                fb0 += 32.0f; fb1 += 32.0f;
            }
        }

        // ======== epilogue: rows m = quad*4+reg = b (quads 0-1 only; 8-15 are dups)
        if (quad < 2) {
            #pragma unroll
            for (int t = 0; t < 2; ++t) {
                int col = 16 * (2 * w + t) + l15;
                #pragma unroll
                for (int reg = 0; reg < 4; ++reg) {
                    int m = quad * 4 + reg;
                    float val = accS[t][reg] + res_lds[m][col];
                    if (layer == 0) {
                        res_lds[m][col] = val;         // next layer's residual
                        xsb[m][col] = (_Float16)val;   // next layer's A-matrix
                    } else {
                        out[((size_t)m * SS + s) * DD + col] = val;
                    }
                }
            }
        }
        if (layer == 0) __syncthreads();
    }
}

extern "C" void kernel_launch(void* const* d_in, const int* in_sizes, int n_in,
                              void* d_out, int out_size, void* d_ws, size_t ws_size,
                              hipStream_t stream)
{
    const float* seq = (const float*)d_in[0];
    const float* M1  = (const float*)d_in[1];
    const float* P1  = (const float*)d_in[2];
    const float* g1  = (const float*)d_in[3];
    const float* b1  = (const float*)d_in[4];
    const float* M2  = (const float*)d_in[5];
    const float* P2  = (const float*)d_in[6];
    const float* g2  = (const float*)d_in[7];
    const float* b2  = (const float*)d_in[8];
    float* out = (float*)d_out;

    if (ws_size >= WS_NEEDED) {
        build_tabs<<<64, 256, 0, stream>>>(M1, P1, M2, P2, (char*)d_ws);
        fused_hierddpm<true><<<SS, 512, 0, stream>>>(
            seq, M1, P1, g1, b1, M2, P2, g2, b2, (const char*)d_ws, out);
    } else {
        fused_hierddpm<false><<<SS, 512, 0, stream>>>(
            seq, M1, P1, g1, b1, M2, P2, g2, b2, nullptr, out);
    }
}

// Round 14
// 112.217 us; speedup vs baseline: 1.3778x; 1.3778x over previous
//
#include <hip/hip_runtime.h>

#define DD 256
#define BB 8
#define SS 1024
#define XSTRIDE 264   // f16 elems per LDS row (528 B, 16B-aligned)
#define RSTRIDE 260   // f32 elems per residual LDS row (1040 B, 16B-aligned)

// ws layout per layer (bytes): Mtab 128K | Ptab 128K | Itab 256K = 512K
#define LAYER_BYTES 524288
#define PTAB_OFF    131072
#define ITAB_OFF    262144
#define WS_NEEDED   (2 * LAYER_BYTES)

typedef _Float16 half8  __attribute__((ext_vector_type(8)));
typedef _Float16 half2t __attribute__((ext_vector_type(2)));
typedef __fp16   fp16x2 __attribute__((ext_vector_type(2)));
typedef __attribute__((ext_vector_type(4))) float float4v;

union h8u { half8 h; half2t h2[4]; };

__device__ __forceinline__ half2t pkrtz(float a, float b) {
    union { fp16x2 f; half2t h; } cv;
    cv.f = __builtin_amdgcn_cvt_pkrtz(a, b);
    return cv.h;
}

__device__ __forceinline__ float cosrev(float x) {   // cos(2*pi*x), any x
    return __builtin_amdgcn_cosf(__builtin_amdgcn_fractf(x));
}
__device__ __forceinline__ float cosq(float x) {     // cos(2*pi*x), x in [0,1)
    return __builtin_amdgcn_cosf(x);
}

// Fragment-ordered tables: for gi = (kt*16 + wt)*64 + lane,
// lane = quad*16 + l15, n = 16*wt+l15, j0 = kt*32+quad*8:
//   Mtab[gi] = M[n][j0..j0+7] (f16), Ptab[gi] = P[n][j0..j0+7] (f16),
//   Itab[2*gi..2*gi+1] = 1/(n*256 + j0 + e + 2), e=0..7 (f32)
__global__ void build_tabs(const float* __restrict__ M1, const float* __restrict__ P1,
                           const float* __restrict__ M2, const float* __restrict__ P2,
                           char* __restrict__ ws)
{
    int gid   = blockIdx.x * 256 + threadIdx.x;   // 0..16383
    int layer = gid >> 13;
    int gi    = gid & 8191;
    int idx   = gi >> 6;                           // kt*16 + wt
    int lane  = gi & 63;
    int wt    = idx & 15;
    int l15   = lane & 15, quad = lane >> 4;
    int kt    = idx >> 4;
    int n     = 16 * wt + l15;
    int j0    = kt * 32 + quad * 8;

    const float* Msrc = layer ? M2 : M1;
    const float* Psrc = layer ? P2 : P1;

    h8u mh, ph;
    float iv[8];
    #pragma unroll
    for (int e = 0; e < 4; ++e) {
        float ma = Msrc[(size_t)n * DD + j0 + 2 * e];
        float mb = Msrc[(size_t)n * DD + j0 + 2 * e + 1];
        float pa = Psrc[(size_t)n * DD + j0 + 2 * e];
        float pb = Psrc[(size_t)n * DD + j0 + 2 * e + 1];
        mh.h2[e] = pkrtz(ma, mb);
        ph.h2[e] = pkrtz(pa, pb);
        iv[2 * e]     = 1.0f / (float)(n * DD + j0 + 2 * e + 2);
        iv[2 * e + 1] = 1.0f / (float)(n * DD + j0 + 2 * e + 3);
    }
    char* base = ws + (size_t)layer * LAYER_BYTES;
    ((half8*)base)[gi]              = mh.h;
    ((half8*)(base + PTAB_OFF))[gi] = ph.h;
    float4* it = (float4*)(base + ITAB_OFF);
    it[2 * gi]     = make_float4(iv[0], iv[1], iv[2], iv[3]);
    it[2 * gi + 1] = make_float4(iv[4], iv[5], iv[6], iv[7]);
}

// Round-6 kernel (best wall: 44.3us, busy 22.3, duty 50%, s-pair blocks grid 512,
// (512,4)) with ONE change: phase-B's 8 v_rcp per tile -> 2 float4 Itab loads
// consumed directly from components (same transient live range as the rcp results
// they replace -- no arrays, no new prefetch regs; the r10/r11/r13 spill trigger
// was ADDED live state, which this avoids). r0-vs-r6 A/B: Itab-vs-rcp = -3.5us
// busy chip-wide. k0/k1 still share each 1/p via a1 = a0 + ia. fract skipped
// where p > k provably (all tiles except w==0,t==0).
template<bool TABS>
__global__ __launch_bounds__(512, 4)
void fused_hierddpm(const float* __restrict__ seq,
                    const float* __restrict__ M1, const float* __restrict__ P1,
                    const float* __restrict__ g1, const float* __restrict__ be1,
                    const float* __restrict__ M2, const float* __restrict__ P2,
                    const float* __restrict__ g2, const float* __restrict__ be2,
                    const char* __restrict__ ws,
                    float* __restrict__ out)
{
    __shared__ __align__(16) _Float16 xsb[16][XSTRIDE];  // input / layer-out, f16
    __shared__ __align__(16) _Float16 xtb[16][XSTRIDE];  // LN'd xt, f16
    __shared__ __align__(16) float2 stats[16][8];        // [row][wave] (sum, sumsq)
    __shared__ __align__(16) float res_lds[16][RSTRIDE]; // f32 residual

    const int tid  = threadIdx.x;
    const int w    = tid >> 6;
    const int lane = tid & 63;
    const int l15  = lane & 15;
    const int quad = lane >> 4;
    const int s0   = blockIdx.x * 2;
    const float k0 = (float)s0;

    // ---- stage x into xsb (f16) and res_lds (f32), one coalesced float4 pass
    {
        const float4* seq4 = (const float4*)seq;
        #pragma unroll
        for (int u = 0; u < 2; ++u) {
            int v  = tid + 512 * u;          // float4 index 0..1023
            int sl = v >> 9;
            int rm = v & 511;
            int b  = rm >> 6, j4 = rm & 63;
            float4 x = seq4[((size_t)b * SS + s0 + sl) * 64 + j4];
            int r = sl * 8 + b;
            half2t* dst = (half2t*)&xsb[r][4 * j4];
            dst[0] = pkrtz(x.x, x.y);
            dst[1] = pkrtz(x.z, x.w);
            *(float4*)&res_lds[r][4 * j4] = x;
        }
    }
    __syncthreads();

    #pragma unroll 1
    for (int layer = 0; layer < 2; ++layer) {
        const float* M  = layer ? M2  : M1;
        const float* P  = layer ? P2  : P1;
        const float* g  = layer ? g2  : g1;
        const float* be = layer ? be2 : be1;
        const char*  lbase = ws + (size_t)layer * LAYER_BYTES;
        const half8*  Mtab = (const half8*)lbase;
        const half8*  Ptab = (const half8*)(lbase + PTAB_OFF);
        const float4* Itab = (const float4*)(lbase + ITAB_OFF);

        // ======== phase A: xt = x @ M^T, distance-1 pipelined
        float4v acc1[2];
        acc1[0] = (float4v){0.f, 0.f, 0.f, 0.f};
        acc1[1] = (float4v){0.f, 0.f, 0.f, 0.f};

        half8 aN = *(const half8*)&xsb[l15][quad * 8];
        half8 b0N, b1N;
        if (TABS) {
            b0N = Mtab[(2 * w) * 64 + lane];
            b1N = Mtab[(2 * w + 1) * 64 + lane];
        }
        #pragma unroll 1
        for (int kt = 0; kt < 8; ++kt) {
            half8 aC = aN;
            half8 b0C, b1C;
            if (TABS) {
                b0C = b0N; b1C = b1N;
            } else {
                #pragma unroll
                for (int t = 0; t < 2; ++t) {
                    int n = 16 * (2 * w + t) + l15;
                    const float4* Mr = (const float4*)M + ((size_t)n * 64 + kt * 8 + quad * 2);
                    float4 m0 = Mr[0], m1 = Mr[1];
                    h8u bb2;
                    bb2.h2[0] = pkrtz(m0.x, m0.y);
                    bb2.h2[1] = pkrtz(m0.z, m0.w);
                    bb2.h2[2] = pkrtz(m1.x, m1.y);
                    bb2.h2[3] = pkrtz(m1.z, m1.w);
                    if (t == 0) b0C = bb2.h; else b1C = bb2.h;
                }
            }
            if (kt < 7) {
                aN = *(const half8*)&xsb[l15][(kt + 1) * 32 + quad * 8];
                if (TABS) {
                    b0N = Mtab[((kt + 1) * 16 + 2 * w) * 64 + lane];
                    b1N = Mtab[((kt + 1) * 16 + 2 * w + 1) * 64 + lane];
                }
            }
            acc1[0] = __builtin_amdgcn_mfma_f32_16x16x32_f16(aC, b0C, acc1[0], 0, 0, 0);
            acc1[1] = __builtin_amdgcn_mfma_f32_16x16x32_f16(aC, b1C, acc1[1], 0, 0, 0);
        }

        // issue phase-B's first Ptab loads NOW: LayerNorm below covers their latency
        half8 p0N, p1N;
        if (TABS) {
            p0N = Ptab[(2 * w) * 64 + lane];
            p1N = Ptab[(2 * w + 1) * 64 + lane];
        }

        // ======== LayerNorm in C-register layout (row m = quad*4+reg)
        #pragma unroll
        for (int reg = 0; reg < 4; ++reg) {
            float v0 = acc1[0][reg], v1 = acc1[1][reg];
            float sm = v0 + v1;
            float sq = fmaf(v0, v0, v1 * v1);
            #pragma unroll
            for (int off = 1; off < 16; off <<= 1) {
                sm += __shfl_xor(sm, off, 64);
                sq += __shfl_xor(sq, off, 64);
            }
            if (l15 == 0) stats[quad * 4 + reg][w] = make_float2(sm, sq);
        }
        __syncthreads();
        {
            int c0i = 16 * (2 * w) + l15, c1i = 16 * (2 * w + 1) + l15;
            float gv0 = g[c0i], bv0 = be[c0i];
            float gv1 = g[c1i], bv1 = be[c1i];
            #pragma unroll
            for (int reg = 0; reg < 4; ++reg) {
                int m = quad * 4 + reg;
                const float4* s4 = (const float4*)&stats[m][0];
                float4 q0 = s4[0], q1 = s4[1], q2 = s4[2], q3 = s4[3];
                float sm = (q0.x + q0.z) + (q1.x + q1.z) + (q2.x + q2.z) + (q3.x + q3.z);
                float sq = (q0.y + q0.w) + (q1.y + q1.w) + (q2.y + q2.w) + (q3.y + q3.w);
                float mm = sm * (1.f / DD);
                float rs = rsqrtf(sq * (1.f / DD) - mm * mm + 1e-5f);
                xtb[m][c0i] = (_Float16)fmaf((acc1[0][reg] - mm) * rs, gv0, bv0);
                xtb[m][c1i] = (_Float16)fmaf((acc1[1][reg] - mm) * rs, gv1, bv1);
            }
        }
        __syncthreads();   // xtb ready for phase B

        // ======== phase B: Nk = xt @ W_s^T; W = P * cos, 1/p from Itab (k0/k1 share)
        float4v accS[2][2];   // [s-half][t]
        #pragma unroll
        for (int k = 0; k < 2; ++k)
            #pragma unroll
            for (int t = 0; t < 2; ++t) accS[k][t] = (float4v){0.f, 0.f, 0.f, 0.f};

        half8 aBN = *(const half8*)&xtb[l15][quad * 8];
        float fb0 = (float)((16 * (2 * w) + l15) * DD + quad * 8 + 2);   // non-TABS
        float fb1 = fb0 + 16.0f * DD;

        #pragma unroll 1
        for (int kt = 0; kt < 8; ++kt) {
            half8 aC = aBN;
            h8u p0C, p1C;
            float4 ia0, ib0, ia1, ib1;
            if (TABS) {
                p0C.h = p0N; p1C.h = p1N;
                int gi0 = (kt * 16 + 2 * w) * 64 + lane;
                int gi1 = gi0 + 64;
                ia0 = Itab[2 * gi0]; ib0 = Itab[2 * gi0 + 1];   // t=0 tile 1/p
                ia1 = Itab[2 * gi1]; ib1 = Itab[2 * gi1 + 1];   // t=1 tile 1/p
            } else {
                #pragma unroll
                for (int t = 0; t < 2; ++t) {
                    int n = 16 * (2 * w + t) + l15;
                    const float4* Pr = (const float4*)P + ((size_t)n * 64 + kt * 8 + quad * 2);
                    float4 p0 = Pr[0], p1 = Pr[1];
                    h8u pv;
                    pv.h2[0] = pkrtz(p0.x, p0.y);
                    pv.h2[1] = pkrtz(p0.z, p0.w);
                    pv.h2[2] = pkrtz(p1.x, p1.y);
                    pv.h2[3] = pkrtz(p1.z, p1.w);
                    if (t == 0) p0C = pv; else p1C = pv;
                }
            }
            if (kt < 7) {
                aBN = *(const half8*)&xtb[l15][(kt + 1) * 32 + quad * 8];
                if (TABS) {
                    p0N = Ptab[((kt + 1) * 16 + 2 * w) * 64 + lane];
                    p1N = Ptab[((kt + 1) * 16 + 2 * w + 1) * 64 + lane];
                }
            }
            // ---- t = 0: n = 32w + l15; w==0 needs exact range-reduce (p down to 2)
            {
                h8u bA, bB;
                if (TABS) {
                    if (w == 0) {
                        float a0, b0f, a1, b1f;
                        a0 = k0 * ia0.x; a1 = a0 + ia0.x;
                        b0f = k0 * ia0.y; b1f = b0f + ia0.y;
                        bA.h2[0] = p0C.h2[0] * pkrtz(cosrev(a0), cosrev(b0f));
                        bB.h2[0] = p0C.h2[0] * pkrtz(cosrev(a1), cosrev(b1f));
                        a0 = k0 * ia0.z; a1 = a0 + ia0.z;
                        b0f = k0 * ia0.w; b1f = b0f + ia0.w;
                        bA.h2[1] = p0C.h2[1] * pkrtz(cosrev(a0), cosrev(b0f));
                        bB.h2[1] = p0C.h2[1] * pkrtz(cosrev(a1), cosrev(b1f));
                        a0 = k0 * ib0.x; a1 = a0 + ib0.x;
                        b0f = k0 * ib0.y; b1f = b0f + ib0.y;
                        bA.h2[2] = p0C.h2[2] * pkrtz(cosrev(a0), cosrev(b0f));
                        bB.h2[2] = p0C.h2[2] * pkrtz(cosrev(a1), cosrev(b1f));
                        a0 = k0 * ib0.z; a1 = a0 + ib0.z;
                        b0f = k0 * ib0.w; b1f = b0f + ib0.w;
                        bA.h2[3] = p0C.h2[3] * pkrtz(cosrev(a0), cosrev(b0f));
                        bB.h2[3] = p0C.h2[3] * pkrtz(cosrev(a1), cosrev(b1f));
                    } else {   // n >= 32 -> p >= 8194 > k+1: fract is identity
                        float a0, b0f, a1, b1f;
                        a0 = k0 * ia0.x; a1 = a0 + ia0.x;
                        b0f = k0 * ia0.y; b1f = b0f + ia0.y;
                        bA.h2[0] = p0C.h2[0] * pkrtz(cosq(a0), cosq(b0f));
                        bB.h2[0] = p0C.h2[0] * pkrtz(cosq(a1), cosq(b1f));
                        a0 = k0 * ia0.z; a1 = a0 + ia0.z;
                        b0f = k0 * ia0.w; b1f = b0f + ia0.w;
                        bA.h2[1] = p0C.h2[1] * pkrtz(cosq(a0), cosq(b0f));
                        bB.h2[1] = p0C.h2[1] * pkrtz(cosq(a1), cosq(b1f));
                        a0 = k0 * ib0.x; a1 = a0 + ib0.x;
                        b0f = k0 * ib0.y; b1f = b0f + ib0.y;
                        bA.h2[2] = p0C.h2[2] * pkrtz(cosq(a0), cosq(b0f));
                        bB.h2[2] = p0C.h2[2] * pkrtz(cosq(a1), cosq(b1f));
                        a0 = k0 * ib0.z; a1 = a0 + ib0.z;
                        b0f = k0 * ib0.w; b1f = b0f + ib0.w;
                        bA.h2[3] = p0C.h2[3] * pkrtz(cosq(a0), cosq(b0f));
                        bB.h2[3] = p0C.h2[3] * pkrtz(cosq(a1), cosq(b1f));
                    }
                } else {
                    #pragma unroll
                    for (int e = 0; e < 4; ++e) {
                        float ra = __builtin_amdgcn_rcpf(fb0 + (float)(2 * e));
                        float rb = __builtin_amdgcn_rcpf(fb0 + (float)(2 * e + 1));
                        float a0 = k0 * ra, b0f = k0 * rb;
                        float a1 = a0 + ra, b1f = b0f + rb;
                        bA.h2[e] = p0C.h2[e] * pkrtz(cosrev(a0), cosrev(b0f));
                        bB.h2[e] = p0C.h2[e] * pkrtz(cosrev(a1), cosrev(b1f));
                    }
                    fb0 += 32.0f;
                }
                accS[0][0] = __builtin_amdgcn_mfma_f32_16x16x32_f16(aC, bA.h, accS[0][0], 0, 0, 0);
                accS[1][0] = __builtin_amdgcn_mfma_f32_16x16x32_f16(aC, bB.h, accS[1][0], 0, 0, 0);
            }
            // ---- t = 1: n >= 16 -> p >= 4098 > k+1: fract-free always
            {
                h8u bA, bB;
                if (TABS) {
                    float a0, b0f, a1, b1f;
                    a0 = k0 * ia1.x; a1 = a0 + ia1.x;
                    b0f = k0 * ia1.y; b1f = b0f + ia1.y;
                    bA.h2[0] = p1C.h2[0] * pkrtz(cosq(a0), cosq(b0f));
                    bB.h2[0] = p1C.h2[0] * pkrtz(cosq(a1), cosq(b1f));
                    a0 = k0 * ia1.z; a1 = a0 + ia1.z;
                    b0f = k0 * ia1.w; b1f = b0f + ia1.w;
                    bA.h2[1] = p1C.h2[1] * pkrtz(cosq(a0), cosq(b0f));
                    bB.h2[1] = p1C.h2[1] * pkrtz(cosq(a1), cosq(b1f));
                    a0 = k0 * ib1.x; a1 = a0 + ib1.x;
                    b0f = k0 * ib1.y; b1f = b0f + ib1.y;
                    bA.h2[2] = p1C.h2[2] * pkrtz(cosq(a0), cosq(b0f));
                    bB.h2[2] = p1C.h2[2] * pkrtz(cosq(a1), cosq(b1f));
                    a0 = k0 * ib1.z; a1 = a0 + ib1.z;
                    b0f = k0 * ib1.w; b1f = b0f + ib1.w;
                    bA.h2[3] = p1C.h2[3] * pkrtz(cosq(a0), cosq(b0f));
                    bB.h2[3] = p1C.h2[3] * pkrtz(cosq(a1), cosq(b1f));
                } else {
                    #pragma unroll
                    for (int e = 0; e < 4; ++e) {
                        float ra = __builtin_amdgcn_rcpf(fb1 + (float)(2 * e));
                        float rb = __builtin_amdgcn_rcpf(fb1 + (float)(2 * e + 1));
                        float a0 = k0 * ra, b0f = k0 * rb;
                        float a1 = a0 + ra, b1f = b0f + rb;
                        bA.h2[e] = p1C.h2[e] * pkrtz(cosrev(a0), cosrev(b0f));
                        bB.h2[e] = p1C.h2[e] * pkrtz(cosrev(a1), cosrev(b1f));
                    }
                    fb1 += 32.0f;
                }
                accS[0][1] = __builtin_amdgcn_mfma_f32_16x16x32_f16(aC, bA.h, accS[0][1], 0, 0, 0);
                accS[1][1] = __builtin_amdgcn_mfma_f32_16x16x32_f16(aC, bB.h, accS[1][1], 0, 0, 0);
            }
        }

        // ======== epilogue: rows 0-7 (quads 0-1) = s0, rows 8-15 (quads 2-3) = s1
        #pragma unroll
        for (int t = 0; t < 2; ++t) {
            int col = 16 * (2 * w + t) + l15;
            float4v av = (quad < 2) ? accS[0][t] : accS[1][t];
            int sl = quad >> 1;
            #pragma unroll
            for (int reg = 0; reg < 4; ++reg) {
                int m = quad * 4 + reg;
                int b = m & 7;
                float val = av[reg] + res_lds[m][col];
                if (layer == 0) {
                    res_lds[m][col] = val;         // next layer's residual
                    xsb[m][col] = (_Float16)val;   // next layer's A-matrix
                } else {
                    out[((size_t)b * SS + s0 + sl) * DD + col] = val;
                }
            }
        }
        if (layer == 0) __syncthreads();
    }
}

extern "C" void kernel_launch(void* const* d_in, const int* in_sizes, int n_in,
                              void* d_out, int out_size, void* d_ws, size_t ws_size,
                              hipStream_t stream)
{
    const float* seq = (const float*)d_in[0];
    const float* M1  = (const float*)d_in[1];
    const float* P1  = (const float*)d_in[2];
    const float* g1  = (const float*)d_in[3];
    const float* b1  = (const float*)d_in[4];
    const float* M2  = (const float*)d_in[5];
    const float* P2  = (const float*)d_in[6];
    const float* g2  = (const float*)d_in[7];
    const float* b2  = (const float*)d_in[8];
    float* out = (float*)d_out;

    if (ws_size >= WS_NEEDED) {
        build_tabs<<<64, 256, 0, stream>>>(M1, P1, M2, P2, (char*)d_ws);
        fused_hierddpm<true><<<SS / 2, 512, 0, stream>>>(
            seq, M1, P1, g1, b1, M2, P2, g2, b2, (const char*)d_ws, out);
    } else {
        fused_hierddpm<false><<<SS / 2, 512, 0, stream>>>(
            seq, M1, P1, g1, b1, M2, P2, g2, b2, nullptr, out);
    }
}